// Round 15
// baseline (342.635 us; speedup 1.0000x reference)
//
#include <hip/hip_runtime.h>
#include <math.h>

// ConvKAN3D: 3x [conv3d(3x3x3,pad1) -> cubic KAN spline + SiLU -> BN(eval) -> maxpool 2x2x2]
// then global mean pool + fc1/relu/fc2.
// r25 == r24 resubmitted (r24 bench was an infra failure: container died twice;
// no kernel signal). WEIGHT LOAD SOFTWARE-PIPELINE (single change vs r23).
// Post-mortem across r16-r23: every decomposition (NSW 1/2, CSPLIT 1/2/4, G 4/8,
// occupancy variants) runs at ~40% of its FMA-issue floor -- the stall is
// config-INVARIANT. The one shared structure: per-gg weight block does
// issue-7-s_loads -> immediate use -> lgkm drain (~250cy scalar-cache latency) ->
// FMA block. Exposed stall = G*250cy vs G*432cy FMA = ~37% = the missing fraction
// (ratio-invariant in G, which is why r20's G=8 was null). Compiler can't pipeline
// it (SGPR budget 112 maxed; needs source-level alternation). Fix: qa/qb double
// buffer -- issue gg+1's (or next step's gg=0, clamped in-bounds) loads BEFORE
// the current FMA block; qa loop-carried across steps; first load hoisted under
// the prologue DMA wait. If loads demote to VGPR-broadcast VMEM they are consumed
// within the step (drained before next stage) so the vmcnt(6) invariant holds.
// Measured-dead-ends (do not retry): direct per-lane global r[] loads (r21:264us),
// reg-staged r[]-prefetch (r18 spill), LDS pad/align (r15), TPB=128 (r13),
// 1 block/CU (r16), separate 1-block head (r17), per-lane weight VGPRs w/ G=8
// (r8), conv-acc global atomics (r5), decomposition reshuffles (r17-r23 all null).
// launch_bounds stays (TPB,2). CSPLIT scratch indexed by (cg,sw_) (r14 race).

#define GLOBAL_AS __attribute__((address_space(1)))
#define LDS_AS    __attribute__((address_space(3)))

static __device__ __forceinline__ void async_ld16(const float* g, float* l) {
    __builtin_amdgcn_global_load_lds((const GLOBAL_AS void*)g, (LDS_AS void*)l,
                                     16, 0, 0);
}

// Pack [C][CIN][27] conv weights -> [C*CIN][28] (16B-aligned float4 x 7, tail 0).
// Tail threads zero zbuf, pooled, and the fc completion counter (replay-safe).
__global__ __launch_bounds__(256) void repack_kernel(
    const float* __restrict__ w1, const float* __restrict__ w2,
    const float* __restrict__ w3,
    float* __restrict__ o1, float* __restrict__ o2, float* __restrict__ o3,
    float* __restrict__ zbuf, float* __restrict__ pooled,
    float* __restrict__ cntf)
{
    const int i = blockIdx.x * 256 + threadIdx.x;   // (c,ci) pair id
    const float* src;
    float* dst;
    if (i < 32)            { src = w1 + i * 27;           dst = o1 + i * 28; }
    else if (i < 2080)     { const int j = i - 32;   src = w2 + j * 27; dst = o2 + j * 28; }
    else if (i < 10272)    { const int j = i - 2080; src = w3 + j * 27; dst = o3 + j * 28; }
    else {
        if (i < 10288) zbuf[i - 10272] = 0.0f;
        else if (i < 10544) pooled[i - 10288] = 0.0f;
        else if (i < 10560) cntf[i - 10544] = 0.0f;
        return;
    }
#pragma unroll
    for (int t = 0; t < 27; t++) dst[t] = src[t];
    dst[27] = 0.0f;
}

template <int TPB_, int CIN, int CSPLIT, int G,
          int WDT, int WHT, int WWT, int BD, int BH, int BW, bool FMEAN>
__global__ __launch_bounds__(TPB_, 2) void spline_block_kernel(
    const float* __restrict__ x,    // [N, CIN, D, H, W]
    const float4* __restrict__ wpk, // [Cout*CIN][7] packed conv weights
    const float* __restrict__ cb,
    const float* __restrict__ knots,
    const float* __restrict__ sw,
    const float* __restrict__ w1,
    const float* __restrict__ w2,
    const float* __restrict__ g,
    const float* __restrict__ beta,
    const float* __restrict__ zbuf, // >=64B of zeros (16B aligned)
    float* __restrict__ out,        // FMEAN? pooled[N*Cout] : [N,Cout,D/2,H/2,W/2]
    const float* __restrict__ fw1, const float* __restrict__ fb1,
    const float* __restrict__ fw2, const float* __restrict__ fb2,
    float* __restrict__ dout, int* __restrict__ cnt,
    int N, int Cout, int D, int H, int W,
    int ntiles, int nthw, int ntw)
{
    constexpr int NSW    = BD * BH * BW;       // spatial wave-tiles per block
    constexpr int NW     = TPB_ / 64;          // waves per block
    constexpr int CPG    = CIN / CSPLIT;       // cins per cin-group
    constexpr int ID     = 2 * WDT + 2;        // input planes (d) per wave tile
    constexpr int IH     = 2 * WHT + 2;        // input rows (h) per wave tile
    constexpr int CHK    = (WWT + 4) / 2;      // 16B chunks per input row
    constexpr int PITCH  = CHK * 4;            // dwords per row
    constexpr int ROWS   = ID * IH;
    constexpr int CHUNKS = ROWS * CHK;
    constexpr int PHYS   = CHUNKS * 4;         // dwords per wave buffer
    constexpr int NCH    = (CHUNKS + 63) / 64; // DMA issues per cin per lane
    constexpr int BUFS   = (CPG > 1) ? 2 : 1;
    // multi-pass reduction sizing: scratch aliases the tile; if one pass doesn't
    // fit, split the G*8 accumulator indices across 2 passes (r22 compile fail).
    constexpr int RED    = G * 8;              // accumulator dwords per thread
    constexpr int CAP    = NW * BUFS * PHYS;   // tile capacity (dwords)
    constexpr int PASSES = (CSPLIT == 1) ? 1
                         : (((CSPLIT - 1) * NSW * 64 * RED <= CAP) ? 1 : 2);
    constexpr int RPP    = RED / PASSES;       // indices per pass
    static_assert(NW == NSW * CSPLIT, "waves = spatial-tiles x cin-split");
    static_assert(WDT * WHT * WWT == 64, "one wave per spatial tile");
    static_assert(CIN % CSPLIT == 0, "cin divisible");
    static_assert(G == 4 || G == 8, "acc layout assumes G in {4,8}");
    static_assert(RED % PASSES == 0, "even pass split");
    static_assert(NCH <= 32, "mask fits u32");
    static_assert(NCH == 6, "s_waitcnt vmcnt(6) literal assumes 6 issues/cin");
    static_assert(CSPLIT == 1 ||
                  (CSPLIT - 1) * NSW * 64 * RPP <= CAP,
                  "reduction scratch fits in tile (per pass)");
    static_assert(!FMEAN || TPB_ == 256, "fused fc assumes 256 threads");

    __shared__ __align__(16) float tile[NW][BUFS][PHYS];
    __shared__ float4 stbl[G * 11];            // spline prefix coeffs {A,3B,3C,D}
    __shared__ int lastblk;

    const int PD = D >> 1, PH = H >> 1, PW = W >> 1;
    const int groups = Cout / G;
    const int tid  = threadIdx.x;
    const int wv   = tid >> 6;                 // wave id
    const int lane = tid & 63;
    const int sw_  = wv % NSW;                 // spatial wave-tile id
    const int cg   = wv / NSW;                 // cin-group id

    const int bx      = blockIdx.x;
    const int tile_id = bx % ntiles;
    const int t1      = bx / ntiles;
    const int grp     = t1 % groups;
    const int n       = t1 / groups;
    const int c0      = grp * G;
    const int cinbase = cg * CPG;
    // wave-uniform cin base -> uniform weight addresses -> SMEM s_load (lgkmcnt,
    // separate counter from the staging DMAs' vmcnt, zero VGPR cost)
    const int cinbase_u = __builtin_amdgcn_readfirstlane(cinbase);

    const int td  = tile_id / nthw;
    const int rem = tile_id % nthw;
    const int th_ = rem / ntw;
    const int tw_ = rem % ntw;

    // spline prefix-coeff table (covered by the single initial barrier)
    for (int i = tid; i < G * 11; i += TPB_) {
        const int gg  = i / 11;
        const int cnt2 = i % 11;
        const int c   = c0 + gg;
        float A = 0.f, B3 = 0.f, C3 = 0.f, Dd = 0.f;
        for (int j = 0; j < cnt2; j++) {
            const float s = sw[c * 10 + j];
            const float k = knots[j];
            A  += s;
            B3 += 3.0f * s * k;
            C3 += 3.0f * s * k * k;
            Dd += s * k * k * k;
        }
        stbl[i] = make_float4(A, B3, C3, Dd);
    }

    // wave spatial origin (pooled coords)
    const int swd = sw_ / (BH * BW);
    const int r2  = sw_ % (BH * BW);
    const int swh = r2 / BW;
    const int sww = r2 % BW;
    const int pd0 = td  * (BD * WDT) + swd * WDT;
    const int ph0 = th_ * (BH * WHT) + swh * WHT;
    const int pw0 = tw_ * (BW * WWT) + sww * WWT;

    const int pwl = lane % WWT;
    const int phl = (lane / WWT) % WHT;
    const int pdl = lane / (WWT * WHT);

    const int d0 = 2 * pd0 - 1, h0 = 2 * ph0 - 1;
    const int w0 = 2 * pw0 - 1;
    const int wb = w0 & ~3;                    // 4-dword aligned chunk origin
    const int woff = w0 - wb;

    // per-chunk global offsets + validity (per wave tile, same for all cins)
    int off[NCH];
    unsigned vm = 0;
#pragma unroll
    for (int k = 0; k < NCH; k++) {
        const int chunk = lane + 64 * k;
        const int row = chunk / CHK, cs = chunk - row * CHK;
        const int dz = row / IH, hy = row - dz * IH;
        const int dd = d0 + dz, hh = h0 + hy;
        const int wsd = wb + cs * 4;
        const bool ok = (chunk < CHUNKS) &
                        ((unsigned)dd < (unsigned)D) &
                        ((unsigned)hh < (unsigned)H) &
                        ((unsigned)wsd < (unsigned)W);
        off[k] = ok ? (dd * H + hh) * W + wsd : 0;
        vm |= (unsigned)ok << k;
    }

    const size_t chstride = (size_t)D * H * W;
    const float* xn = x + (size_t)n * CIN * chstride;

    float acc[G][8];
#pragma unroll
    for (int gg = 0; gg < G; gg++)
#pragma unroll
        for (int i = 0; i < 8; i++) acc[gg][i] = 0.0f;

    __syncthreads();   // stbl visible; vmcnt drained (clean slate)

    auto stage = [&](int ci, int buf) {
        const float* xc = xn + (size_t)ci * chstride;
        float* dst = &tile[wv][buf][0];
#pragma unroll
        for (int k = 0; k < NCH; k++) {
            const int chunk = lane + 64 * k;
            if ((k + 1) * 64 <= CHUNKS || chunk < CHUNKS) {
                const float* src = ((vm >> k) & 1) ? (xc + off[k]) : zbuf;
                async_ld16(src, dst + chunk * 4);
            }
        }
    };

    // prologue: each wave stages its first cin into its buf 0
    stage(cinbase, 0);

    // weight software-pipeline: qa holds the current (cout,cin) weight block.
    // The NEXT block is issued before each FMA block (latency hides under the
    // 216/432-cycle FMA run). First load hides under the prologue DMA wait.
    float4 qa[7];
    {
        const float4* wq0 = wpk + ((size_t)c0 * CIN + cinbase_u) * 7;
#pragma unroll
        for (int ch = 0; ch < 7; ch++) qa[ch] = wq0[ch];
    }

#pragma unroll 1
    for (int s = 0; s < CPG; s++) {
        const int cur = s & (BUFS - 1);
        if (s + 1 < CPG) {
            stage(cinbase + s + 1, cur ^ 1);   // 6 DMA issues, stay in flight
            asm volatile("s_waitcnt vmcnt(6)" ::: "memory");  // cin s landed
        } else {
            asm volatile("s_waitcnt vmcnt(0)" ::: "memory");
        }

        const int ci_u = cinbase_u + s;        // wave-uniform weight row
        const float* tb = &tile[wv][cur][0];
        float r[64];
#pragma unroll
        for (int dz = 0; dz < 4; dz++)
#pragma unroll
        for (int dy = 0; dy < 4; dy++) {
            const int rb = ((2 * pdl + dz) * IH + (2 * phl + dy)) * PITCH +
                           woff + 2 * pwl;
            r[(dz * 4 + dy) * 4 + 0] = tb[rb + 0];
            r[(dz * 4 + dy) * 4 + 1] = tb[rb + 1];
            r[(dz * 4 + dy) * 4 + 2] = tb[rb + 2];
            r[(dz * 4 + dy) * 4 + 3] = tb[rb + 3];
        }

#pragma unroll
        for (int gg = 0; gg < G; gg++) {
            // issue next weight block: gg+1 of this cin, or gg=0 of the next cin.
            // The final iteration's overread (ci_u+1) is clamped in-bounds of wpk
            // (reads the next cout-row's cin 0) and never consumed.
            const float4* wqn = wpk + ((gg + 1 < G)
                ? ((size_t)(c0 + gg + 1) * CIN + ci_u) * 7
                : ((size_t)c0 * CIN + ci_u + 1) * 7);
            float4 qb[7];
#pragma unroll
            for (int ch = 0; ch < 7; ch++) qb[ch] = wqn[ch];

#pragma unroll
            for (int ch = 0; ch < 7; ch++) {
#pragma unroll
                for (int j = 0; j < 4; j++) {
                    const int tap = ch * 4 + j;
                    if (tap < 27) {
                        const float wvj = (j == 0) ? qa[ch].x : (j == 1) ? qa[ch].y
                                        : (j == 2) ? qa[ch].z : qa[ch].w;
                        const int kd = tap / 9, kh = (tap % 9) / 3, kw = tap % 3;
#pragma unroll
                        for (int od = 0; od < 2; od++)
#pragma unroll
                        for (int oh = 0; oh < 2; oh++)
#pragma unroll
                        for (int ow = 0; ow < 2; ow++)
                            acc[gg][(od * 2 + oh) * 2 + ow] =
                                fmaf(wvj,
                                     r[((od + kd) * 4 + (oh + kh)) * 4 + (ow + kw)],
                                     acc[gg][(od * 2 + oh) * 2 + ow]);
                    }
                }
            }

#pragma unroll
            for (int ch = 0; ch < 7; ch++) qa[ch] = qb[ch];
        }
    }

    // combine partial accumulators across cin-groups (scratch aliases tile),
    // in PASSES chunks of RPP indices (capacity-limited; r22 compile fail).
    // scratch MUST be indexed by (cg, sw_) jointly (r14 replay race).
    float* af = &acc[0][0];
    if (CSPLIT > 1) {
#pragma unroll
        for (int p = 0; p < PASSES; p++) {
            __syncthreads();   // p=0: waves done with tiles; p>0: readers done
            float* scratch = &tile[0][0][0];
            if (cg > 0) {
#pragma unroll
                for (int ii = 0; ii < RPP; ii++)
                    scratch[((ii * (CSPLIT - 1) + (cg - 1)) * NSW + sw_) * 64 + lane]
                        = af[p * RPP + ii];
            }
            __syncthreads();
            if (cg == 0) {
#pragma unroll
                for (int ii = 0; ii < RPP; ii++) {
                    float s2 = af[p * RPP + ii];
                    for (int j = 0; j < CSPLIT - 1; j++)
                        s2 += scratch[((ii * (CSPLIT - 1) + j) * NSW + sw_) * 64 + lane];
                    af[p * RPP + ii] = s2;
                }
            }
        }
    }

    // epilogue (cin-group 0): bias + spline (prefix-Horner) + SiLU + BN + maxpool
    if (cg == 0) {
        const int pdg = pd0 + pdl, phg = ph0 + phl, pwg = pw0 + pwl;
        const float inv_vol = 1.0f / (float)(PD * PH * PW);
#pragma unroll
        for (int gg = 0; gg < G; gg++) {
            const int c = c0 + gg;
            const float bias = cb[c];
            const float W1 = w1[c], W2 = w2[c];
            const float scale = g[c] * rsqrtf(1.0f + 1e-5f);
            const float bb = beta[c];
            float m = -INFINITY;
#pragma unroll
            for (int i = 0; i < 8; i++) {
                const float y = acc[gg][i] + bias;
                int idx = (int)floorf((y + 1.0f) * 4.5f) + 1;
                idx = min(max(idx, 0), 10);
                const float4 cf = stbl[gg * 11 + idx];
                const float sp = ((cf.x * y - cf.y) * y + cf.z) * y - cf.w;
                const float silu = y / (1.0f + __expf(-y));
                const float o = fmaf(W1 * sp + W2 * silu, scale, bb);
                m = fmaxf(m, o);
            }
            if constexpr (FMEAN) {
                float ssum = m;
#pragma unroll
                for (int o2 = 32; o2 > 0; o2 >>= 1)
                    ssum += __shfl_down(ssum, o2, 64);
                if (lane == 0)
                    atomicAdd(&out[(size_t)n * Cout + c], ssum * inv_vol);
            } else {
                out[((size_t)(n * Cout + c) * PD + pdg) * PH * PW +
                    phg * PW + pwg] = m;
            }
        }
    }

    // fused fc head: LAST block (device-scope counter) computes fc1/fc2.
    if constexpr (FMEAN) {
        __syncthreads();   // per-wave vmcnt(0) drain -> all atomics retired
        if (tid == 0) {
            __threadfence();                         // publish this block's adds
            lastblk = (atomicAdd(cnt, 1) == (int)gridDim.x - 1);
        }
        __syncthreads();
        if (lastblk) {
            __threadfence();                         // order before coherent reads
            float* fl = &tile[0][0][0];              // plds[256] | hb[2][256]
            fl[tid] = atomicAdd(&out[tid], 0.0f);    // coherent read of pooled
            __syncthreads();
#pragma unroll
            for (int nn = 0; nn < 2; nn++) {
                float s = fb1[tid];
                for (int k = 0; k < 128; k++)
                    s = fmaf(fl[nn * 128 + k], fw1[tid * 128 + k], s);
                fl[256 + nn * 256 + tid] = fmaxf(s, 0.0f);
            }
            __syncthreads();
            const int wid = tid >> 6, l2 = tid & 63;
            const int nn = wid >> 1, oo = wid & 1;
            float s = 0.0f;
            for (int k = l2; k < 256; k += 64)
                s += fl[256 + nn * 256 + k] * fw2[oo * 256 + k];
#pragma unroll
            for (int o2 = 32; o2 > 0; o2 >>= 1) s += __shfl_down(s, o2, 64);
            if (l2 == 0) dout[nn * 2 + oo] = s + fb2[oo];
        }
    }
}

extern "C" void kernel_launch(void* const* d_in, const int* in_sizes, int n_in,
                              void* d_out, int out_size, void* d_ws, size_t ws_size,
                              hipStream_t stream) {
    const float* x      = (const float*)d_in[0];
    const float* c1_w   = (const float*)d_in[1];
    const float* c1_b   = (const float*)d_in[2];
    const float* c1_kn  = (const float*)d_in[3];
    const float* c1_sw  = (const float*)d_in[4];
    const float* c1_w1  = (const float*)d_in[5];
    const float* c1_w2  = (const float*)d_in[6];
    const float* bn1_g  = (const float*)d_in[7];
    const float* bn1_b  = (const float*)d_in[8];
    const float* c2_w   = (const float*)d_in[9];
    const float* c2_b   = (const float*)d_in[10];
    const float* c2_kn  = (const float*)d_in[11];
    const float* c2_sw  = (const float*)d_in[12];
    const float* c2_w1  = (const float*)d_in[13];
    const float* c2_w2  = (const float*)d_in[14];
    const float* bn2_g  = (const float*)d_in[15];
    const float* bn2_b  = (const float*)d_in[16];
    const float* c3_w   = (const float*)d_in[17];
    const float* c3_b   = (const float*)d_in[18];
    const float* c3_kn  = (const float*)d_in[19];
    const float* c3_sw  = (const float*)d_in[20];
    const float* c3_w1  = (const float*)d_in[21];
    const float* c3_w2  = (const float*)d_in[22];
    const float* bn3_g  = (const float*)d_in[23];
    const float* bn3_b  = (const float*)d_in[24];
    const float* fc1_w  = (const float*)d_in[25];
    const float* fc1_b  = (const float*)d_in[26];
    const float* fc2_w  = (const float*)d_in[27];
    const float* fc2_b  = (const float*)d_in[28];

    float* ws = (float*)d_ws;
    float* h1     = ws;                  // 2*32*32^3 = 2,097,152 fl
    float* h2     = h1 + 2097152;        // 2*64*16^3 =   524,288 fl
    float* pooled = h2 + 524288;         // 256 fl (atomic accumulator)
    float* zbuf   = pooled + 256;        // 64 B zeros (16B aligned)
    float* cntf   = zbuf + 16;           // 16 fl (fc completion counter at [0])
    float* wp1    = cntf + 16;           // 32*1*28   =       896 fl (16B aligned)
    float* wp2    = wp1 + 896;           // 64*32*28  =    57,344 fl
    float* wp3    = wp2 + 57344;         // 128*64*28 =   229,376 fl

    // pack conv weights (pitch-28 float4x7) + zero zbuf/pooled/cnt (replay-safe)
    repack_kernel<<<dim3(42), dim3(256), 0, stream>>>(
        c1_w, c2_w, c3_w, wp1, wp2, wp3, zbuf, pooled, cntf);

    // All layers: wave tile 2x4x8 (ID=6, IH=10, PITCH=24, 6 DMA issues/cin).
    // L1: (2,1,64^3)->(2,32,32^3). r12 config (measured 33.6us): 4 spatial
    // waves (2x2x1), grid 2048.
    spline_block_kernel<256, 1, 1, 4, 2, 4, 8, 2, 2, 1, false>
        <<<dim3(2048), dim3(256), 0, stream>>>(
        x, (const float4*)wp1, c1_b, c1_kn, c1_sw, c1_w1, c1_w2, bn1_g, bn1_b,
        zbuf, h1, nullptr, nullptr, nullptr, nullptr, nullptr, nullptr,
        2, 32, 64, 64, 64, 128, 16, 4);
    // L2: (2,32,32^3)->(2,64,16^3). CSPLIT=4 x NSW=1, G=8, CPG=8, grid 1024.
    // (r23 config, 117.3us measured; this round adds only weight pipelining.)
    spline_block_kernel<256, 32, 4, 8, 2, 4, 8, 1, 1, 1, false>
        <<<dim3(1024), dim3(256), 0, stream>>>(
        h1, (const float4*)wp2, c2_b, c2_kn, c2_sw, c2_w1, c2_w2, bn2_g, bn2_b,
        zbuf, h2, nullptr, nullptr, nullptr, nullptr, nullptr, nullptr,
        2, 64, 32, 32, 32, 64, 8, 2);
    // L3: (2,64,16^3)->pooled[2,128] (FMEAN) + last-block fused fc -> d_out.
    // CSPLIT=4, grid 512.
    spline_block_kernel<256, 64, 4, 4, 2, 4, 8, 1, 1, 1, true>
        <<<dim3(512), dim3(256), 0, stream>>>(
        h2, (const float4*)wp3, c3_b, c3_kn, c3_sw, c3_w1, c3_w2, bn3_g, bn3_b,
        zbuf, pooled, fc1_w, fc1_b, fc2_w, fc2_b, (float*)d_out, (int*)cntf,
        2, 128, 16, 16, 16, 8, 2, 1);
}

// Round 16
// 320.453 us; speedup vs baseline: 1.0692x; 1.0692x over previous
//
#include <hip/hip_runtime.h>
#include <math.h>

// ConvKAN3D: 3x [conv3d(3x3x3,pad1) -> cubic KAN spline + SiLU -> BN(eval) -> maxpool 2x2x2]
// then global mean pool + fc1/relu/fc2.
// r26: REVERT to r23 (session best, 318.5us measured). r25's weight software-
// pipeline (qa/qb double-buffer) REGRESSED L2 117.3->144us (VALUBusy 61->52):
// the per-iteration qa=qb copy chain + conditional next-block address serialized
// the loop and added VGPR pressure instead of hiding scalar-cache latency.
// Theory scorecard (all measured-null or regressions; do not retry):
//   DS pressure (r20: G=8 halved DS/FMA, conflict ctr halved, dur null)
//   occupancy/residency (r17/r18/r23 reshapes: null or spill)
//   weight pipelining (r25: -27us regression)
//   direct per-lane global r[] loads (r21: 264us, TA/L1 saturation, 14x amplif.)
//   reg-staged r[]-prefetch (r18: scratch spill, WRITE 964MB)
//   LDS pad/align (r15: conflict counter structural, unchanged)
//   TPB=128 (r13), 1 block/CU (r16), separate 1-block fused head (r17),
//   per-lane weight VGPRs w/ G=8 (r8), conv-acc global atomics (r5).
// Kept wins: scalar s_load weights via readfirstlane (r16), fused mean via
// atomicAdd + last-block fc in L3 (r19/r20), repack kernel w/ zero-tail.
// The staged structure runs at a config-invariant ~40% of its VALU floor;
// further gains require an algorithm change (e.g. split-bf16 MFMA), not tuning.
// launch_bounds stays (TPB,2). CSPLIT scratch indexed by (cg,sw_) (r14 race).

#define GLOBAL_AS __attribute__((address_space(1)))
#define LDS_AS    __attribute__((address_space(3)))

static __device__ __forceinline__ void async_ld16(const float* g, float* l) {
    __builtin_amdgcn_global_load_lds((const GLOBAL_AS void*)g, (LDS_AS void*)l,
                                     16, 0, 0);
}

// Pack [C][CIN][27] conv weights -> [C*CIN][28] (16B-aligned float4 x 7, tail 0).
// Tail threads zero zbuf, pooled, and the fc completion counter (replay-safe).
__global__ __launch_bounds__(256) void repack_kernel(
    const float* __restrict__ w1, const float* __restrict__ w2,
    const float* __restrict__ w3,
    float* __restrict__ o1, float* __restrict__ o2, float* __restrict__ o3,
    float* __restrict__ zbuf, float* __restrict__ pooled,
    float* __restrict__ cntf)
{
    const int i = blockIdx.x * 256 + threadIdx.x;   // (c,ci) pair id
    const float* src;
    float* dst;
    if (i < 32)            { src = w1 + i * 27;           dst = o1 + i * 28; }
    else if (i < 2080)     { const int j = i - 32;   src = w2 + j * 27; dst = o2 + j * 28; }
    else if (i < 10272)    { const int j = i - 2080; src = w3 + j * 27; dst = o3 + j * 28; }
    else {
        if (i < 10288) zbuf[i - 10272] = 0.0f;
        else if (i < 10544) pooled[i - 10288] = 0.0f;
        else if (i < 10560) cntf[i - 10544] = 0.0f;
        return;
    }
#pragma unroll
    for (int t = 0; t < 27; t++) dst[t] = src[t];
    dst[27] = 0.0f;
}

template <int TPB_, int CIN, int CSPLIT, int G,
          int WDT, int WHT, int WWT, int BD, int BH, int BW, bool FMEAN>
__global__ __launch_bounds__(TPB_, 2) void spline_block_kernel(
    const float* __restrict__ x,    // [N, CIN, D, H, W]
    const float4* __restrict__ wpk, // [Cout*CIN][7] packed conv weights
    const float* __restrict__ cb,
    const float* __restrict__ knots,
    const float* __restrict__ sw,
    const float* __restrict__ w1,
    const float* __restrict__ w2,
    const float* __restrict__ g,
    const float* __restrict__ beta,
    const float* __restrict__ zbuf, // >=64B of zeros (16B aligned)
    float* __restrict__ out,        // FMEAN? pooled[N*Cout] : [N,Cout,D/2,H/2,W/2]
    const float* __restrict__ fw1, const float* __restrict__ fb1,
    const float* __restrict__ fw2, const float* __restrict__ fb2,
    float* __restrict__ dout, int* __restrict__ cnt,
    int N, int Cout, int D, int H, int W,
    int ntiles, int nthw, int ntw)
{
    constexpr int NSW    = BD * BH * BW;       // spatial wave-tiles per block
    constexpr int NW     = TPB_ / 64;          // waves per block
    constexpr int CPG    = CIN / CSPLIT;       // cins per cin-group
    constexpr int ID     = 2 * WDT + 2;        // input planes (d) per wave tile
    constexpr int IH     = 2 * WHT + 2;        // input rows (h) per wave tile
    constexpr int CHK    = (WWT + 4) / 2;      // 16B chunks per input row
    constexpr int PITCH  = CHK * 4;            // dwords per row
    constexpr int ROWS   = ID * IH;
    constexpr int CHUNKS = ROWS * CHK;
    constexpr int PHYS   = CHUNKS * 4;         // dwords per wave buffer
    constexpr int NCH    = (CHUNKS + 63) / 64; // DMA issues per cin per lane
    constexpr int BUFS   = (CPG > 1) ? 2 : 1;
    // multi-pass reduction sizing: scratch aliases the tile; if one pass doesn't
    // fit, split the G*8 accumulator indices across 2 passes (r22 compile fail).
    constexpr int RED    = G * 8;              // accumulator dwords per thread
    constexpr int CAP    = NW * BUFS * PHYS;   // tile capacity (dwords)
    constexpr int PASSES = (CSPLIT == 1) ? 1
                         : (((CSPLIT - 1) * NSW * 64 * RED <= CAP) ? 1 : 2);
    constexpr int RPP    = RED / PASSES;       // indices per pass
    static_assert(NW == NSW * CSPLIT, "waves = spatial-tiles x cin-split");
    static_assert(WDT * WHT * WWT == 64, "one wave per spatial tile");
    static_assert(CIN % CSPLIT == 0, "cin divisible");
    static_assert(G == 4 || G == 8, "acc layout assumes G in {4,8}");
    static_assert(RED % PASSES == 0, "even pass split");
    static_assert(NCH <= 32, "mask fits u32");
    static_assert(NCH == 6, "s_waitcnt vmcnt(6) literal assumes 6 issues/cin");
    static_assert(CSPLIT == 1 ||
                  (CSPLIT - 1) * NSW * 64 * RPP <= CAP,
                  "reduction scratch fits in tile (per pass)");
    static_assert(!FMEAN || TPB_ == 256, "fused fc assumes 256 threads");

    __shared__ __align__(16) float tile[NW][BUFS][PHYS];
    __shared__ float4 stbl[G * 11];            // spline prefix coeffs {A,3B,3C,D}
    __shared__ int lastblk;

    const int PD = D >> 1, PH = H >> 1, PW = W >> 1;
    const int groups = Cout / G;
    const int tid  = threadIdx.x;
    const int wv   = tid >> 6;                 // wave id
    const int lane = tid & 63;
    const int sw_  = wv % NSW;                 // spatial wave-tile id
    const int cg   = wv / NSW;                 // cin-group id

    const int bx      = blockIdx.x;
    const int tile_id = bx % ntiles;
    const int t1      = bx / ntiles;
    const int grp     = t1 % groups;
    const int n       = t1 / groups;
    const int c0      = grp * G;
    const int cinbase = cg * CPG;
    // wave-uniform cin base -> uniform weight addresses -> SMEM s_load (lgkmcnt,
    // separate counter from the staging DMAs' vmcnt, zero VGPR cost)
    const int cinbase_u = __builtin_amdgcn_readfirstlane(cinbase);

    const int td  = tile_id / nthw;
    const int rem = tile_id % nthw;
    const int th_ = rem / ntw;
    const int tw_ = rem % ntw;

    // spline prefix-coeff table (covered by the single initial barrier)
    for (int i = tid; i < G * 11; i += TPB_) {
        const int gg  = i / 11;
        const int cnt2 = i % 11;
        const int c   = c0 + gg;
        float A = 0.f, B3 = 0.f, C3 = 0.f, Dd = 0.f;
        for (int j = 0; j < cnt2; j++) {
            const float s = sw[c * 10 + j];
            const float k = knots[j];
            A  += s;
            B3 += 3.0f * s * k;
            C3 += 3.0f * s * k * k;
            Dd += s * k * k * k;
        }
        stbl[i] = make_float4(A, B3, C3, Dd);
    }

    // wave spatial origin (pooled coords)
    const int swd = sw_ / (BH * BW);
    const int r2  = sw_ % (BH * BW);
    const int swh = r2 / BW;
    const int sww = r2 % BW;
    const int pd0 = td  * (BD * WDT) + swd * WDT;
    const int ph0 = th_ * (BH * WHT) + swh * WHT;
    const int pw0 = tw_ * (BW * WWT) + sww * WWT;

    const int pwl = lane % WWT;
    const int phl = (lane / WWT) % WHT;
    const int pdl = lane / (WWT * WHT);

    const int d0 = 2 * pd0 - 1, h0 = 2 * ph0 - 1;
    const int w0 = 2 * pw0 - 1;
    const int wb = w0 & ~3;                    // 4-dword aligned chunk origin
    const int woff = w0 - wb;

    // per-chunk global offsets + validity (per wave tile, same for all cins)
    int off[NCH];
    unsigned vm = 0;
#pragma unroll
    for (int k = 0; k < NCH; k++) {
        const int chunk = lane + 64 * k;
        const int row = chunk / CHK, cs = chunk - row * CHK;
        const int dz = row / IH, hy = row - dz * IH;
        const int dd = d0 + dz, hh = h0 + hy;
        const int wsd = wb + cs * 4;
        const bool ok = (chunk < CHUNKS) &
                        ((unsigned)dd < (unsigned)D) &
                        ((unsigned)hh < (unsigned)H) &
                        ((unsigned)wsd < (unsigned)W);
        off[k] = ok ? (dd * H + hh) * W + wsd : 0;
        vm |= (unsigned)ok << k;
    }

    const size_t chstride = (size_t)D * H * W;
    const float* xn = x + (size_t)n * CIN * chstride;

    float acc[G][8];
#pragma unroll
    for (int gg = 0; gg < G; gg++)
#pragma unroll
        for (int i = 0; i < 8; i++) acc[gg][i] = 0.0f;

    __syncthreads();   // stbl visible; vmcnt drained (clean slate)

    auto stage = [&](int ci, int buf) {
        const float* xc = xn + (size_t)ci * chstride;
        float* dst = &tile[wv][buf][0];
#pragma unroll
        for (int k = 0; k < NCH; k++) {
            const int chunk = lane + 64 * k;
            if ((k + 1) * 64 <= CHUNKS || chunk < CHUNKS) {
                const float* src = ((vm >> k) & 1) ? (xc + off[k]) : zbuf;
                async_ld16(src, dst + chunk * 4);
            }
        }
    };

    // prologue: each wave stages its first cin into its buf 0
    stage(cinbase, 0);

#pragma unroll 1
    for (int s = 0; s < CPG; s++) {
        const int cur = s & (BUFS - 1);
        if (s + 1 < CPG) {
            stage(cinbase + s + 1, cur ^ 1);   // 6 DMA issues, stay in flight
            asm volatile("s_waitcnt vmcnt(6)" ::: "memory");  // cin s landed
        } else {
            asm volatile("s_waitcnt vmcnt(0)" ::: "memory");
        }

        const int ci_u = cinbase_u + s;        // wave-uniform weight row
        const float* tb = &tile[wv][cur][0];
        float r[64];
#pragma unroll
        for (int dz = 0; dz < 4; dz++)
#pragma unroll
        for (int dy = 0; dy < 4; dy++) {
            const int rb = ((2 * pdl + dz) * IH + (2 * phl + dy)) * PITCH +
                           woff + 2 * pwl;
            r[(dz * 4 + dy) * 4 + 0] = tb[rb + 0];
            r[(dz * 4 + dy) * 4 + 1] = tb[rb + 1];
            r[(dz * 4 + dy) * 4 + 2] = tb[rb + 2];
            r[(dz * 4 + dy) * 4 + 3] = tb[rb + 3];
        }

#pragma unroll
        for (int gg = 0; gg < G; gg++) {
            // uniform address -> s_load (SMEM), separate lgkm counter
            const float4* wq = wpk + ((size_t)(c0 + gg) * CIN + ci_u) * 7;
            float4 q[7];
#pragma unroll
            for (int ch = 0; ch < 7; ch++) q[ch] = wq[ch];
#pragma unroll
            for (int ch = 0; ch < 7; ch++) {
#pragma unroll
                for (int j = 0; j < 4; j++) {
                    const int tap = ch * 4 + j;
                    if (tap < 27) {
                        const float wvj = (j == 0) ? q[ch].x : (j == 1) ? q[ch].y
                                        : (j == 2) ? q[ch].z : q[ch].w;
                        const int kd = tap / 9, kh = (tap % 9) / 3, kw = tap % 3;
#pragma unroll
                        for (int od = 0; od < 2; od++)
#pragma unroll
                        for (int oh = 0; oh < 2; oh++)
#pragma unroll
                        for (int ow = 0; ow < 2; ow++)
                            acc[gg][(od * 2 + oh) * 2 + ow] =
                                fmaf(wvj,
                                     r[((od + kd) * 4 + (oh + kh)) * 4 + (ow + kw)],
                                     acc[gg][(od * 2 + oh) * 2 + ow]);
                    }
                }
            }
        }
    }

    // combine partial accumulators across cin-groups (scratch aliases tile),
    // in PASSES chunks of RPP indices (capacity-limited; r22 compile fail).
    // scratch MUST be indexed by (cg, sw_) jointly (r14 replay race).
    float* af = &acc[0][0];
    if (CSPLIT > 1) {
#pragma unroll
        for (int p = 0; p < PASSES; p++) {
            __syncthreads();   // p=0: waves done with tiles; p>0: readers done
            float* scratch = &tile[0][0][0];
            if (cg > 0) {
#pragma unroll
                for (int ii = 0; ii < RPP; ii++)
                    scratch[((ii * (CSPLIT - 1) + (cg - 1)) * NSW + sw_) * 64 + lane]
                        = af[p * RPP + ii];
            }
            __syncthreads();
            if (cg == 0) {
#pragma unroll
                for (int ii = 0; ii < RPP; ii++) {
                    float s2 = af[p * RPP + ii];
                    for (int j = 0; j < CSPLIT - 1; j++)
                        s2 += scratch[((ii * (CSPLIT - 1) + j) * NSW + sw_) * 64 + lane];
                    af[p * RPP + ii] = s2;
                }
            }
        }
    }

    // epilogue (cin-group 0): bias + spline (prefix-Horner) + SiLU + BN + maxpool
    if (cg == 0) {
        const int pdg = pd0 + pdl, phg = ph0 + phl, pwg = pw0 + pwl;
        const float inv_vol = 1.0f / (float)(PD * PH * PW);
#pragma unroll
        for (int gg = 0; gg < G; gg++) {
            const int c = c0 + gg;
            const float bias = cb[c];
            const float W1 = w1[c], W2 = w2[c];
            const float scale = g[c] * rsqrtf(1.0f + 1e-5f);
            const float bb = beta[c];
            float m = -INFINITY;
#pragma unroll
            for (int i = 0; i < 8; i++) {
                const float y = acc[gg][i] + bias;
                int idx = (int)floorf((y + 1.0f) * 4.5f) + 1;
                idx = min(max(idx, 0), 10);
                const float4 cf = stbl[gg * 11 + idx];
                const float sp = ((cf.x * y - cf.y) * y + cf.z) * y - cf.w;
                const float silu = y / (1.0f + __expf(-y));
                const float o = fmaf(W1 * sp + W2 * silu, scale, bb);
                m = fmaxf(m, o);
            }
            if constexpr (FMEAN) {
                float ssum = m;
#pragma unroll
                for (int o2 = 32; o2 > 0; o2 >>= 1)
                    ssum += __shfl_down(ssum, o2, 64);
                if (lane == 0)
                    atomicAdd(&out[(size_t)n * Cout + c], ssum * inv_vol);
            } else {
                out[((size_t)(n * Cout + c) * PD + pdg) * PH * PW +
                    phg * PW + pwg] = m;
            }
        }
    }

    // fused fc head: LAST block (device-scope counter) computes fc1/fc2.
    if constexpr (FMEAN) {
        __syncthreads();   // per-wave vmcnt(0) drain -> all atomics retired
        if (tid == 0) {
            __threadfence();                         // publish this block's adds
            lastblk = (atomicAdd(cnt, 1) == (int)gridDim.x - 1);
        }
        __syncthreads();
        if (lastblk) {
            __threadfence();                         // order before coherent reads
            float* fl = &tile[0][0][0];              // plds[256] | hb[2][256]
            fl[tid] = atomicAdd(&out[tid], 0.0f);    // coherent read of pooled
            __syncthreads();
#pragma unroll
            for (int nn = 0; nn < 2; nn++) {
                float s = fb1[tid];
                for (int k = 0; k < 128; k++)
                    s = fmaf(fl[nn * 128 + k], fw1[tid * 128 + k], s);
                fl[256 + nn * 256 + tid] = fmaxf(s, 0.0f);
            }
            __syncthreads();
            const int wid = tid >> 6, l2 = tid & 63;
            const int nn = wid >> 1, oo = wid & 1;
            float s = 0.0f;
            for (int k = l2; k < 256; k += 64)
                s += fl[256 + nn * 256 + k] * fw2[oo * 256 + k];
#pragma unroll
            for (int o2 = 32; o2 > 0; o2 >>= 1) s += __shfl_down(s, o2, 64);
            if (l2 == 0) dout[nn * 2 + oo] = s + fb2[oo];
        }
    }
}

extern "C" void kernel_launch(void* const* d_in, const int* in_sizes, int n_in,
                              void* d_out, int out_size, void* d_ws, size_t ws_size,
                              hipStream_t stream) {
    const float* x      = (const float*)d_in[0];
    const float* c1_w   = (const float*)d_in[1];
    const float* c1_b   = (const float*)d_in[2];
    const float* c1_kn  = (const float*)d_in[3];
    const float* c1_sw  = (const float*)d_in[4];
    const float* c1_w1  = (const float*)d_in[5];
    const float* c1_w2  = (const float*)d_in[6];
    const float* bn1_g  = (const float*)d_in[7];
    const float* bn1_b  = (const float*)d_in[8];
    const float* c2_w   = (const float*)d_in[9];
    const float* c2_b   = (const float*)d_in[10];
    const float* c2_kn  = (const float*)d_in[11];
    const float* c2_sw  = (const float*)d_in[12];
    const float* c2_w1  = (const float*)d_in[13];
    const float* c2_w2  = (const float*)d_in[14];
    const float* bn2_g  = (const float*)d_in[15];
    const float* bn2_b  = (const float*)d_in[16];
    const float* c3_w   = (const float*)d_in[17];
    const float* c3_b   = (const float*)d_in[18];
    const float* c3_kn  = (const float*)d_in[19];
    const float* c3_sw  = (const float*)d_in[20];
    const float* c3_w1  = (const float*)d_in[21];
    const float* c3_w2  = (const float*)d_in[22];
    const float* bn3_g  = (const float*)d_in[23];
    const float* bn3_b  = (const float*)d_in[24];
    const float* fc1_w  = (const float*)d_in[25];
    const float* fc1_b  = (const float*)d_in[26];
    const float* fc2_w  = (const float*)d_in[27];
    const float* fc2_b  = (const float*)d_in[28];

    float* ws = (float*)d_ws;
    float* h1     = ws;                  // 2*32*32^3 = 2,097,152 fl
    float* h2     = h1 + 2097152;        // 2*64*16^3 =   524,288 fl
    float* pooled = h2 + 524288;         // 256 fl (atomic accumulator)
    float* zbuf   = pooled + 256;        // 64 B zeros (16B aligned)
    float* cntf   = zbuf + 16;           // 16 fl (fc completion counter at [0])
    float* wp1    = cntf + 16;           // 32*1*28   =       896 fl (16B aligned)
    float* wp2    = wp1 + 896;           // 64*32*28  =    57,344 fl
    float* wp3    = wp2 + 57344;         // 128*64*28 =   229,376 fl

    // pack conv weights (pitch-28 float4x7) + zero zbuf/pooled/cnt (replay-safe)
    repack_kernel<<<dim3(42), dim3(256), 0, stream>>>(
        c1_w, c2_w, c3_w, wp1, wp2, wp3, zbuf, pooled, cntf);

    // All layers: wave tile 2x4x8 (ID=6, IH=10, PITCH=24, 6 DMA issues/cin).
    // L1: (2,1,64^3)->(2,32,32^3). r12 config (measured 33.6us): 4 spatial
    // waves (2x2x1), grid 2048.
    spline_block_kernel<256, 1, 1, 4, 2, 4, 8, 2, 2, 1, false>
        <<<dim3(2048), dim3(256), 0, stream>>>(
        x, (const float4*)wp1, c1_b, c1_kn, c1_sw, c1_w1, c1_w2, bn1_g, bn1_b,
        zbuf, h1, nullptr, nullptr, nullptr, nullptr, nullptr, nullptr,
        2, 32, 64, 64, 64, 128, 16, 4);
    // L2: (2,32,32^3)->(2,64,16^3). CSPLIT=4 x NSW=1, G=8, CPG=8, grid 1024.
    // (r23 config, 117.3us measured.)
    spline_block_kernel<256, 32, 4, 8, 2, 4, 8, 1, 1, 1, false>
        <<<dim3(1024), dim3(256), 0, stream>>>(
        h1, (const float4*)wp2, c2_b, c2_kn, c2_sw, c2_w1, c2_w2, bn2_g, bn2_b,
        zbuf, h2, nullptr, nullptr, nullptr, nullptr, nullptr, nullptr,
        2, 64, 32, 32, 32, 64, 8, 2);
    // L3: (2,64,16^3)->pooled[2,128] (FMEAN) + last-block fused fc -> d_out.
    // CSPLIT=4, grid 512.
    spline_block_kernel<256, 64, 4, 4, 2, 4, 8, 1, 1, 1, true>
        <<<dim3(512), dim3(256), 0, stream>>>(
        h2, (const float4*)wp3, c3_b, c3_kn, c3_sw, c3_w1, c3_w2, bn3_g, bn3_b,
        zbuf, pooled, fc1_w, fc1_b, fc2_w, fc2_b, (float*)d_out, (int*)cntf,
        2, 128, 16, 16, 16, 8, 2, 1);
}

// Round 20
// 320.308 us; speedup vs baseline: 1.0697x; 1.0005x over previous
//
#include <hip/hip_runtime.h>
#include <math.h>

// ConvKAN3D: 3x [conv3d(3x3x3,pad1) -> cubic KAN spline + SiLU -> BN(eval) -> maxpool 2x2x2]
// then global mean pool + fc1/relu/fc2.
// r30 == r29 resubmitted (r29 bench was an infra failure: container died twice;
// source is byte-identical to r26, which measured 320.5us / 318.5us @r23).
// FINAL KERNEL — verified session best.
// Wins kept vs session baseline (338-342us): barrier-free K-loop with counted
// s_waitcnt vmcnt(6) (r11), scalar s_load weights via readfirstlane (r16),
// fused global-mean via atomicAdd + last-block fc inside L3 (r19/r20),
// dispatch diet 6->4 kernels (r19), repack kernel with zero-tail.
// Theory scorecard (measured-null/regressions; do not retry): DS pressure (r20),
// occupancy reshapes (r17/r18/r23), weight pipelining (r25: -27us), direct
// per-lane r[] loads (r21: 264us), reg-staged r[] prefetch (r18 spill), LDS
// pad/align (r15), TPB=128 (r13), 1 block/CU (r16), per-lane weight VGPRs w/
// G=8 (r8), conv-acc global atomics (r5), cooperative fusion (r27/r28: launch
// silently failed — identical absmax across fence variants proved d_out stayed
// memset-zero). Residual: config-invariant stall ~60% of the staged structure's
// VALU floor; closing it needs an algorithmic rewrite (im2col+MFMA), not tuning.
// launch_bounds stays (TPB,2). CSPLIT scratch indexed by (cg,sw_) (r14 race);
// multi-pass reduction when scratch exceeds tile capacity (r22).

#define GLOBAL_AS __attribute__((address_space(1)))
#define LDS_AS    __attribute__((address_space(3)))

static __device__ __forceinline__ void async_ld16(const float* g, float* l) {
    __builtin_amdgcn_global_load_lds((const GLOBAL_AS void*)g, (LDS_AS void*)l,
                                     16, 0, 0);
}

// Pack [C][CIN][27] conv weights -> [C*CIN][28] (16B-aligned float4 x 7, tail 0).
// Tail threads zero zbuf, pooled, and the fc completion counter (replay-safe).
__global__ __launch_bounds__(256) void repack_kernel(
    const float* __restrict__ w1, const float* __restrict__ w2,
    const float* __restrict__ w3,
    float* __restrict__ o1, float* __restrict__ o2, float* __restrict__ o3,
    float* __restrict__ zbuf, float* __restrict__ pooled,
    float* __restrict__ cntf)
{
    const int i = blockIdx.x * 256 + threadIdx.x;   // (c,ci) pair id
    const float* src;
    float* dst;
    if (i < 32)            { src = w1 + i * 27;           dst = o1 + i * 28; }
    else if (i < 2080)     { const int j = i - 32;   src = w2 + j * 27; dst = o2 + j * 28; }
    else if (i < 10272)    { const int j = i - 2080; src = w3 + j * 27; dst = o3 + j * 28; }
    else {
        if (i < 10288) zbuf[i - 10272] = 0.0f;
        else if (i < 10544) pooled[i - 10288] = 0.0f;
        else if (i < 10560) cntf[i - 10544] = 0.0f;
        return;
    }
#pragma unroll
    for (int t = 0; t < 27; t++) dst[t] = src[t];
    dst[27] = 0.0f;
}

template <int TPB_, int CIN, int CSPLIT, int G,
          int WDT, int WHT, int WWT, int BD, int BH, int BW, bool FMEAN>
__global__ __launch_bounds__(TPB_, 2) void spline_block_kernel(
    const float* __restrict__ x,    // [N, CIN, D, H, W]
    const float4* __restrict__ wpk, // [Cout*CIN][7] packed conv weights
    const float* __restrict__ cb,
    const float* __restrict__ knots,
    const float* __restrict__ sw,
    const float* __restrict__ w1,
    const float* __restrict__ w2,
    const float* __restrict__ g,
    const float* __restrict__ beta,
    const float* __restrict__ zbuf, // >=64B of zeros (16B aligned)
    float* __restrict__ out,        // FMEAN? pooled[N*Cout] : [N,Cout,D/2,H/2,W/2]
    const float* __restrict__ fw1, const float* __restrict__ fb1,
    const float* __restrict__ fw2, const float* __restrict__ fb2,
    float* __restrict__ dout, int* __restrict__ cnt,
    int N, int Cout, int D, int H, int W,
    int ntiles, int nthw, int ntw)
{
    constexpr int NSW    = BD * BH * BW;       // spatial wave-tiles per block
    constexpr int NW     = TPB_ / 64;          // waves per block
    constexpr int CPG    = CIN / CSPLIT;       // cins per cin-group
    constexpr int ID     = 2 * WDT + 2;        // input planes (d) per wave tile
    constexpr int IH     = 2 * WHT + 2;        // input rows (h) per wave tile
    constexpr int CHK    = (WWT + 4) / 2;      // 16B chunks per input row
    constexpr int PITCH  = CHK * 4;            // dwords per row
    constexpr int ROWS   = ID * IH;
    constexpr int CHUNKS = ROWS * CHK;
    constexpr int PHYS   = CHUNKS * 4;         // dwords per wave buffer
    constexpr int NCH    = (CHUNKS + 63) / 64; // DMA issues per cin per lane
    constexpr int BUFS   = (CPG > 1) ? 2 : 1;
    // multi-pass reduction sizing: scratch aliases the tile; if one pass doesn't
    // fit, split the G*8 accumulator indices across 2 passes (r22 compile fail).
    constexpr int RED    = G * 8;              // accumulator dwords per thread
    constexpr int CAP    = NW * BUFS * PHYS;   // tile capacity (dwords)
    constexpr int PASSES = (CSPLIT == 1) ? 1
                         : (((CSPLIT - 1) * NSW * 64 * RED <= CAP) ? 1 : 2);
    constexpr int RPP    = RED / PASSES;       // indices per pass
    static_assert(NW == NSW * CSPLIT, "waves = spatial-tiles x cin-split");
    static_assert(WDT * WHT * WWT == 64, "one wave per spatial tile");
    static_assert(CIN % CSPLIT == 0, "cin divisible");
    static_assert(G == 4 || G == 8, "acc layout assumes G in {4,8}");
    static_assert(RED % PASSES == 0, "even pass split");
    static_assert(NCH <= 32, "mask fits u32");
    static_assert(NCH == 6, "s_waitcnt vmcnt(6) literal assumes 6 issues/cin");
    static_assert(CSPLIT == 1 ||
                  (CSPLIT - 1) * NSW * 64 * RPP <= CAP,
                  "reduction scratch fits in tile (per pass)");
    static_assert(!FMEAN || TPB_ == 256, "fused fc assumes 256 threads");

    __shared__ __align__(16) float tile[NW][BUFS][PHYS];
    __shared__ float4 stbl[G * 11];            // spline prefix coeffs {A,3B,3C,D}
    __shared__ int lastblk;

    const int PD = D >> 1, PH = H >> 1, PW = W >> 1;
    const int groups = Cout / G;
    const int tid  = threadIdx.x;
    const int wv   = tid >> 6;                 // wave id
    const int lane = tid & 63;
    const int sw_  = wv % NSW;                 // spatial wave-tile id
    const int cg   = wv / NSW;                 // cin-group id

    const int bx      = blockIdx.x;
    const int tile_id = bx % ntiles;
    const int t1      = bx / ntiles;
    const int grp     = t1 % groups;
    const int n       = t1 / groups;
    const int c0      = grp * G;
    const int cinbase = cg * CPG;
    // wave-uniform cin base -> uniform weight addresses -> SMEM s_load (lgkmcnt,
    // separate counter from the staging DMAs' vmcnt, zero VGPR cost)
    const int cinbase_u = __builtin_amdgcn_readfirstlane(cinbase);

    const int td  = tile_id / nthw;
    const int rem = tile_id % nthw;
    const int th_ = rem / ntw;
    const int tw_ = rem % ntw;

    // spline prefix-coeff table (covered by the single initial barrier)
    for (int i = tid; i < G * 11; i += TPB_) {
        const int gg  = i / 11;
        const int cnt2 = i % 11;
        const int c   = c0 + gg;
        float A = 0.f, B3 = 0.f, C3 = 0.f, Dd = 0.f;
        for (int j = 0; j < cnt2; j++) {
            const float s = sw[c * 10 + j];
            const float k = knots[j];
            A  += s;
            B3 += 3.0f * s * k;
            C3 += 3.0f * s * k * k;
            Dd += s * k * k * k;
        }
        stbl[i] = make_float4(A, B3, C3, Dd);
    }

    // wave spatial origin (pooled coords)
    const int swd = sw_ / (BH * BW);
    const int r2  = sw_ % (BH * BW);
    const int swh = r2 / BW;
    const int sww = r2 % BW;
    const int pd0 = td  * (BD * WDT) + swd * WDT;
    const int ph0 = th_ * (BH * WHT) + swh * WHT;
    const int pw0 = tw_ * (BW * WWT) + sww * WWT;

    const int pwl = lane % WWT;
    const int phl = (lane / WWT) % WHT;
    const int pdl = lane / (WWT * WHT);

    const int d0 = 2 * pd0 - 1, h0 = 2 * ph0 - 1;
    const int w0 = 2 * pw0 - 1;
    const int wb = w0 & ~3;                    // 4-dword aligned chunk origin
    const int woff = w0 - wb;

    // per-chunk global offsets + validity (per wave tile, same for all cins)
    int off[NCH];
    unsigned vm = 0;
#pragma unroll
    for (int k = 0; k < NCH; k++) {
        const int chunk = lane + 64 * k;
        const int row = chunk / CHK, cs = chunk - row * CHK;
        const int dz = row / IH, hy = row - dz * IH;
        const int dd = d0 + dz, hh = h0 + hy;
        const int wsd = wb + cs * 4;
        const bool ok = (chunk < CHUNKS) &
                        ((unsigned)dd < (unsigned)D) &
                        ((unsigned)hh < (unsigned)H) &
                        ((unsigned)wsd < (unsigned)W);
        off[k] = ok ? (dd * H + hh) * W + wsd : 0;
        vm |= (unsigned)ok << k;
    }

    const size_t chstride = (size_t)D * H * W;
    const float* xn = x + (size_t)n * CIN * chstride;

    float acc[G][8];
#pragma unroll
    for (int gg = 0; gg < G; gg++)
#pragma unroll
        for (int i = 0; i < 8; i++) acc[gg][i] = 0.0f;

    __syncthreads();   // stbl visible; vmcnt drained (clean slate)

    auto stage = [&](int ci, int buf) {
        const float* xc = xn + (size_t)ci * chstride;
        float* dst = &tile[wv][buf][0];
#pragma unroll
        for (int k = 0; k < NCH; k++) {
            const int chunk = lane + 64 * k;
            if ((k + 1) * 64 <= CHUNKS || chunk < CHUNKS) {
                const float* src = ((vm >> k) & 1) ? (xc + off[k]) : zbuf;
                async_ld16(src, dst + chunk * 4);
            }
        }
    };

    // prologue: each wave stages its first cin into its buf 0
    stage(cinbase, 0);

#pragma unroll 1
    for (int s = 0; s < CPG; s++) {
        const int cur = s & (BUFS - 1);
        if (s + 1 < CPG) {
            stage(cinbase + s + 1, cur ^ 1);   // 6 DMA issues, stay in flight
            asm volatile("s_waitcnt vmcnt(6)" ::: "memory");  // cin s landed
        } else {
            asm volatile("s_waitcnt vmcnt(0)" ::: "memory");
        }

        const int ci_u = cinbase_u + s;        // wave-uniform weight row
        const float* tb = &tile[wv][cur][0];
        float r[64];
#pragma unroll
        for (int dz = 0; dz < 4; dz++)
#pragma unroll
        for (int dy = 0; dy < 4; dy++) {
            const int rb = ((2 * pdl + dz) * IH + (2 * phl + dy)) * PITCH +
                           woff + 2 * pwl;
            r[(dz * 4 + dy) * 4 + 0] = tb[rb + 0];
            r[(dz * 4 + dy) * 4 + 1] = tb[rb + 1];
            r[(dz * 4 + dy) * 4 + 2] = tb[rb + 2];
            r[(dz * 4 + dy) * 4 + 3] = tb[rb + 3];
        }

#pragma unroll
        for (int gg = 0; gg < G; gg++) {
            // uniform address -> s_load (SMEM), separate lgkm counter
            const float4* wq = wpk + ((size_t)(c0 + gg) * CIN + ci_u) * 7;
            float4 q[7];
#pragma unroll
            for (int ch = 0; ch < 7; ch++) q[ch] = wq[ch];
#pragma unroll
            for (int ch = 0; ch < 7; ch++) {
#pragma unroll
                for (int j = 0; j < 4; j++) {
                    const int tap = ch * 4 + j;
                    if (tap < 27) {
                        const float wvj = (j == 0) ? q[ch].x : (j == 1) ? q[ch].y
                                        : (j == 2) ? q[ch].z : q[ch].w;
                        const int kd = tap / 9, kh = (tap % 9) / 3, kw = tap % 3;
#pragma unroll
                        for (int od = 0; od < 2; od++)
#pragma unroll
                        for (int oh = 0; oh < 2; oh++)
#pragma unroll
                        for (int ow = 0; ow < 2; ow++)
                            acc[gg][(od * 2 + oh) * 2 + ow] =
                                fmaf(wvj,
                                     r[((od + kd) * 4 + (oh + kh)) * 4 + (ow + kw)],
                                     acc[gg][(od * 2 + oh) * 2 + ow]);
                    }
                }
            }
        }
    }

    // combine partial accumulators across cin-groups (scratch aliases tile),
    // in PASSES chunks of RPP indices (capacity-limited; r22 compile fail).
    // scratch MUST be indexed by (cg, sw_) jointly (r14 replay race).
    float* af = &acc[0][0];
    if (CSPLIT > 1) {
#pragma unroll
        for (int p = 0; p < PASSES; p++) {
            __syncthreads();   // p=0: waves done with tiles; p>0: readers done
            float* scratch = &tile[0][0][0];
            if (cg > 0) {
#pragma unroll
                for (int ii = 0; ii < RPP; ii++)
                    scratch[((ii * (CSPLIT - 1) + (cg - 1)) * NSW + sw_) * 64 + lane]
                        = af[p * RPP + ii];
            }
            __syncthreads();
            if (cg == 0) {
#pragma unroll
                for (int ii = 0; ii < RPP; ii++) {
                    float s2 = af[p * RPP + ii];
                    for (int j = 0; j < CSPLIT - 1; j++)
                        s2 += scratch[((ii * (CSPLIT - 1) + j) * NSW + sw_) * 64 + lane];
                    af[p * RPP + ii] = s2;
                }
            }
        }
    }

    // epilogue (cin-group 0): bias + spline (prefix-Horner) + SiLU + BN + maxpool
    if (cg == 0) {
        const int pdg = pd0 + pdl, phg = ph0 + phl, pwg = pw0 + pwl;
        const float inv_vol = 1.0f / (float)(PD * PH * PW);
#pragma unroll
        for (int gg = 0; gg < G; gg++) {
            const int c = c0 + gg;
            const float bias = cb[c];
            const float W1 = w1[c], W2 = w2[c];
            const float scale = g[c] * rsqrtf(1.0f + 1e-5f);
            const float bb = beta[c];
            float m = -INFINITY;
#pragma unroll
            for (int i = 0; i < 8; i++) {
                const float y = acc[gg][i] + bias;
                int idx = (int)floorf((y + 1.0f) * 4.5f) + 1;
                idx = min(max(idx, 0), 10);
                const float4 cf = stbl[gg * 11 + idx];
                const float sp = ((cf.x * y - cf.y) * y + cf.z) * y - cf.w;
                const float silu = y / (1.0f + __expf(-y));
                const float o = fmaf(W1 * sp + W2 * silu, scale, bb);
                m = fmaxf(m, o);
            }
            if constexpr (FMEAN) {
                float ssum = m;
#pragma unroll
                for (int o2 = 32; o2 > 0; o2 >>= 1)
                    ssum += __shfl_down(ssum, o2, 64);
                if (lane == 0)
                    atomicAdd(&out[(size_t)n * Cout + c], ssum * inv_vol);
            } else {
                out[((size_t)(n * Cout + c) * PD + pdg) * PH * PW +
                    phg * PW + pwg] = m;
            }
        }
    }

    // fused fc head: LAST block (device-scope counter) computes fc1/fc2.
    if constexpr (FMEAN) {
        __syncthreads();   // per-wave vmcnt(0) drain -> all atomics retired
        if (tid == 0) {
            __threadfence();                         // publish this block's adds
            lastblk = (atomicAdd(cnt, 1) == (int)gridDim.x - 1);
        }
        __syncthreads();
        if (lastblk) {
            __threadfence();                         // order before coherent reads
            float* fl = &tile[0][0][0];              // plds[256] | hb[2][256]
            fl[tid] = atomicAdd(&out[tid], 0.0f);    // coherent read of pooled
            __syncthreads();
#pragma unroll
            for (int nn = 0; nn < 2; nn++) {
                float s = fb1[tid];
                for (int k = 0; k < 128; k++)
                    s = fmaf(fl[nn * 128 + k], fw1[tid * 128 + k], s);
                fl[256 + nn * 256 + tid] = fmaxf(s, 0.0f);
            }
            __syncthreads();
            const int wid = tid >> 6, l2 = tid & 63;
            const int nn = wid >> 1, oo = wid & 1;
            float s = 0.0f;
            for (int k = l2; k < 256; k += 64)
                s += fl[256 + nn * 256 + k] * fw2[oo * 256 + k];
#pragma unroll
            for (int o2 = 32; o2 > 0; o2 >>= 1) s += __shfl_down(s, o2, 64);
            if (l2 == 0) dout[nn * 2 + oo] = s + fb2[oo];
        }
    }
}

extern "C" void kernel_launch(void* const* d_in, const int* in_sizes, int n_in,
                              void* d_out, int out_size, void* d_ws, size_t ws_size,
                              hipStream_t stream) {
    const float* x      = (const float*)d_in[0];
    const float* c1_w   = (const float*)d_in[1];
    const float* c1_b   = (const float*)d_in[2];
    const float* c1_kn  = (const float*)d_in[3];
    const float* c1_sw  = (const float*)d_in[4];
    const float* c1_w1  = (const float*)d_in[5];
    const float* c1_w2  = (const float*)d_in[6];
    const float* bn1_g  = (const float*)d_in[7];
    const float* bn1_b  = (const float*)d_in[8];
    const float* c2_w   = (const float*)d_in[9];
    const float* c2_b   = (const float*)d_in[10];
    const float* c2_kn  = (const float*)d_in[11];
    const float* c2_sw  = (const float*)d_in[12];
    const float* c2_w1  = (const float*)d_in[13];
    const float* c2_w2  = (const float*)d_in[14];
    const float* bn2_g  = (const float*)d_in[15];
    const float* bn2_b  = (const float*)d_in[16];
    const float* c3_w   = (const float*)d_in[17];
    const float* c3_b   = (const float*)d_in[18];
    const float* c3_kn  = (const float*)d_in[19];
    const float* c3_sw  = (const float*)d_in[20];
    const float* c3_w1  = (const float*)d_in[21];
    const float* c3_w2  = (const float*)d_in[22];
    const float* bn3_g  = (const float*)d_in[23];
    const float* bn3_b  = (const float*)d_in[24];
    const float* fc1_w  = (const float*)d_in[25];
    const float* fc1_b  = (const float*)d_in[26];
    const float* fc2_w  = (const float*)d_in[27];
    const float* fc2_b  = (const float*)d_in[28];

    float* ws = (float*)d_ws;
    float* h1     = ws;                  // 2*32*32^3 = 2,097,152 fl
    float* h2     = h1 + 2097152;        // 2*64*16^3 =   524,288 fl
    float* pooled = h2 + 524288;         // 256 fl (atomic accumulator)
    float* zbuf   = pooled + 256;        // 64 B zeros (16B aligned)
    float* cntf   = zbuf + 16;           // 16 fl (fc completion counter at [0])
    float* wp1    = cntf + 16;           // 32*1*28   =       896 fl (16B aligned)
    float* wp2    = wp1 + 896;           // 64*32*28  =    57,344 fl
    float* wp3    = wp2 + 57344;         // 128*64*28 =   229,376 fl

    // pack conv weights (pitch-28 float4x7) + zero zbuf/pooled/cnt (replay-safe)
    repack_kernel<<<dim3(42), dim3(256), 0, stream>>>(
        c1_w, c2_w, c3_w, wp1, wp2, wp3, zbuf, pooled, cntf);

    // All layers: wave tile 2x4x8 (ID=6, IH=10, PITCH=24, 6 DMA issues/cin).
    // L1: (2,1,64^3)->(2,32,32^3). r12 config (measured 33.6us): 4 spatial
    // waves (2x2x1), grid 2048.
    spline_block_kernel<256, 1, 1, 4, 2, 4, 8, 2, 2, 1, false>
        <<<dim3(2048), dim3(256), 0, stream>>>(
        x, (const float4*)wp1, c1_b, c1_kn, c1_sw, c1_w1, c1_w2, bn1_g, bn1_b,
        zbuf, h1, nullptr, nullptr, nullptr, nullptr, nullptr, nullptr,
        2, 32, 64, 64, 64, 128, 16, 4);
    // L2: (2,32,32^3)->(2,64,16^3). CSPLIT=4 x NSW=1, G=8, CPG=8, grid 1024.
    // (r23/r26 config, 117.0us measured.)
    spline_block_kernel<256, 32, 4, 8, 2, 4, 8, 1, 1, 1, false>
        <<<dim3(1024), dim3(256), 0, stream>>>(
        h1, (const float4*)wp2, c2_b, c2_kn, c2_sw, c2_w1, c2_w2, bn2_g, bn2_b,
        zbuf, h2, nullptr, nullptr, nullptr, nullptr, nullptr, nullptr,
        2, 64, 32, 32, 32, 64, 8, 2);
    // L3: (2,64,16^3)->pooled[2,128] (FMEAN) + last-block fused fc -> d_out.
    // CSPLIT=4, grid 512.
    spline_block_kernel<256, 64, 4, 4, 2, 4, 8, 1, 1, 1, true>
        <<<dim3(512), dim3(256), 0, stream>>>(
        h2, (const float4*)wp3, c3_b, c3_kn, c3_sw, c3_w1, c3_w2, bn3_g, bn3_b,
        zbuf, pooled, fc1_w, fc1_b, fc2_w, fc2_b, (float*)d_out, (int*)cntf,
        2, 128, 16, 16, 16, 8, 2, 1);
}